// Round 7
// baseline (364.491 us; speedup 1.0000x reference)
//
#include <hip/hip_runtime.h>
#include <hip/hip_bf16.h>

#define OUTF 1024
#define NROWS 65536
#define NBR 4
#define XBROWS 66560     // 256-aligned branch segments upper bound
#define NWG 1040         // 260 M-tiles * 4 N-tiles, %8==0

typedef __attribute__((ext_vector_type(8))) short short8;
typedef __attribute__((ext_vector_type(4))) float f32x4;

__device__ inline unsigned short f2bf(float f) {
    return __builtin_bit_cast(unsigned short, (__bf16)f);
}
__device__ inline void gload_lds16(const void* g, void* l) {
    __builtin_amdgcn_global_load_lds(
        (const __attribute__((address_space(1))) void*)g,
        (__attribute__((address_space(3))) void*)l, 16, 0, 0);
}
__device__ inline short8 pack8(float4 a, float4 b) {
    short8 o;
    o[0] = (short)f2bf(a.x); o[1] = (short)f2bf(a.y);
    o[2] = (short)f2bf(a.z); o[3] = (short)f2bf(a.w);
    o[4] = (short)f2bf(b.x); o[5] = (short)f2bf(b.y);
    o[6] = (short)f2bf(b.z); o[7] = (short)f2bf(b.w);
    return o;
}

#define VMCNT(n) asm volatile("s_waitcnt vmcnt(" #n ")" ::: "memory")
#define SBAR() do { __builtin_amdgcn_s_barrier(); __builtin_amdgcn_sched_barrier(0); } while (0)

// ws int layout: [0..3] counts, [4..7] segment bases (256-aligned), [8..11] fill pos
__global__ void k_count(const int* __restrict__ feat, int* __restrict__ cnt) {
    __shared__ int lc[NBR];
    int tid = threadIdx.x;
    if (tid < NBR) lc[tid] = 0;
    __syncthreads();
    int r = blockIdx.x * 256 + tid;
    int b = 26 - __clz(feat[r]);  // 32->0, 64->1, 128->2, 256->3
    atomicAdd(&lc[b], 1);
    __syncthreads();
    if (tid < NBR && lc[tid]) atomicAdd(&cnt[tid], lc[tid]);
}

__global__ void k_prefix(int* __restrict__ ws) {
    if (threadIdx.x == 0) {
        int s = 0;
        for (int b = 0; b < NBR; b++) {
            ws[4 + b] = s;
            s = (s + ws[b] + 255) & ~255;
            ws[8 + b] = 0;
        }
    }
}

__global__ void k_fill(const int* __restrict__ feat, int* __restrict__ ws,
                       int* __restrict__ rowlist) {
    int tid = threadIdx.x;
    int lane = tid & 63;
    int r = blockIdx.x * 256 + tid;
    int b = 26 - __clz(feat[r]);
    #pragma unroll
    for (int bb = 0; bb < NBR; bb++) {
        unsigned long long mask = __ballot(b == bb);
        int leader = __ffsll((long long)mask) - 1;
        int cntw = __popcll(mask);
        int basepos = 0;
        if (lane == leader) basepos = atomicAdd(&ws[8 + bb], cntw);
        basepos = __shfl(basepos, leader < 0 ? 0 : leader);
        if (b == bb) {
            int prefix = __popcll(mask & ((1ull << lane) - 1ull));
            rowlist[ws[4 + bb] + basepos + prefix] = r;
        }
    }
}

// W fp32 -> bf16, plain linear row-major (1024 N x 1024 K per branch)
__global__ void k_convw(const float* __restrict__ w, unsigned short* __restrict__ wb) {
    int i = ((int)blockIdx.x * 256 + (int)threadIdx.x) * 8;
    const float4* s = reinterpret_cast<const float4*>(w + i);
    *reinterpret_cast<short8*>(wb + i) = pack8(s[0], s[1]);
}

// x fp32 -> bf16, gathered into permuted (branch-contiguous, 256-aligned) order, linear
__global__ void k_convx(const float* __restrict__ x, const int* __restrict__ rowlist,
                        unsigned short* __restrict__ xb) {
    int g = (int)blockIdx.x * 512 + (int)threadIdx.x;   // 16B-out chunks
    int orow = g >> 7;
    int cb = (g & 127) << 4;     // byte col within 2048B row
    int rl = rowlist[orow];
    if ((unsigned)rl >= NROWS) rl = 0;   // pad-gap rows -> row 0 (finite garbage)
    const float4* s = reinterpret_cast<const float4*>(x + (size_t)rl * OUTF + (cb >> 1));
    *reinterpret_cast<short8*>(reinterpret_cast<char*>(xb) + (size_t)orow * 2048 + cb) =
        pack8(s[0], s[1]);
}

// 256x256x64 GEMM, 8 waves (2M x 4N), fine-phase unit pipeline.
// Staging unit = 16 KB = (A|B, K-slice32): 256 rows x 32 K, 64 B/row (ds_read
// fragments are 1024B-contiguous per wave -> conflict-free, no swizzle).
// 9-slot LDS ring (144 KiB). 4 phases/K-tile; unit issued ~6 phases before use;
// counted vmcnt(8) twice per tile (before barrier) -> queue never drains.
__global__ __launch_bounds__(512, 2)
void k_gemm6(const unsigned short* __restrict__ xb,
             const unsigned short* __restrict__ wb,
             const float* __restrict__ bias,
             const int* __restrict__ ws_i,
             const int* __restrict__ rowlist,
             float* __restrict__ out) {
    extern __shared__ char lds[];

    // XCD-chunk swizzle, M-tile-major within chunk (A-panel L2 reuse across 4 N-tiles)
    const int d = (int)blockIdx.x;
    const int work = (d & 7) * (NWG >> 3) + (d >> 3);
    const int mtile = work >> 2;
    const int ntile = work & 3;

    int branch = -1, lt = 0, cnt = 0, rbase = 0;
    int t_ = mtile;
    #pragma unroll
    for (int b = 0; b < NBR; b++) {
        if (branch < 0) {
            int c = ws_i[b];
            int nt = (c + 255) >> 8;
            if (t_ < nt) { branch = b; lt = t_; cnt = c; rbase = ws_i[4 + b]; }
            else t_ -= nt;
        }
    }
    if (branch < 0) return;

    const int tid = threadIdx.x;
    const int lane = tid & 63;
    const int w8 = tid >> 6;
    const int wm = (w8 >> 2) * 128;   // 0/128
    const int wn = (w8 & 3) * 64;     // 0/64/128/192
    const int n0 = ntile * 256;
    const int row0 = rbase + lt * 256;

    // staging: thread covers row (tid>>2) and (tid>>2)+128, 16B col (tid&3)*16 of each unit
    const char* aSrc = reinterpret_cast<const char*>(xb)
                       + (size_t)(row0 + (tid >> 2)) * 2048 + ((tid & 3) << 4);
    const char* bSrc = reinterpret_cast<const char*>(wb) + ((size_t)branch << 21)
                       + (size_t)(n0 + (tid >> 2)) * 2048 + ((tid & 3) << 4);
    const int ldst = tid << 4;

    // fragment read offsets within a unit (row stride 64B)
    const int aoff = (wm + (lane & 15)) * 64 + ((lane >> 4) << 4);
    const int boff = (wn + (lane & 15)) * 64 + ((lane >> 4) << 4);

    f32x4 acc[8][4];
    #pragma unroll
    for (int i = 0; i < 8; i++)
        #pragma unroll
        for (int j = 0; j < 4; j++) acc[i][j] = (f32x4){0.f, 0.f, 0.f, 0.f};

    // unit u: tile u>>2; (u&1): 0=A,1=B; slice (u>>1)&1. slot = u % 9.
    #define STAGE(u) do {                                                  \
        const int _sl = (u) % 9;                                           \
        const char* _s = ((u) & 1) ? bSrc : aSrc;                          \
        const int _kb = (((u) >> 2) << 7) + ((((u) >> 1) & 1) << 6);       \
        char* _d = lds + _sl * 16384 + ldst;                               \
        gload_lds16(_s + _kb, _d);                                         \
        gload_lds16(_s + 262144 + _kb, _d + 8192);                         \
    } while (0)

    // prologue: units 0..5 (tile0 all 4 + tile1 A-s0,B-s0)
    STAGE(0); STAGE(1); STAGE(2); STAGE(3); STAGE(4); STAGE(5);
    VMCNT(8);          // u0,u1 landed; 8 loads in flight
    SBAR();

    short8 af[8], b0, b1;

    for (int t = 0; t < 16; ++t) {
        const int b4 = 4 * t;
        char* A0 = lds + (b4 % 9) * 16384;
        char* B0 = lds + ((b4 + 1) % 9) * 16384;
        char* A1 = lds + ((b4 + 2) % 9) * 16384;
        char* B1 = lds + ((b4 + 3) % 9) * 16384;

        // ---- p0: slice0, acc cols 0,1. Issue u=b4+6 (A-s1 of t+1).
        if (t < 15) STAGE(b4 + 6);
        #pragma unroll
        for (int i = 0; i < 8; i++)
            af[i] = *reinterpret_cast<const short8*>(A0 + aoff + i * 1024);
        b0 = *reinterpret_cast<const short8*>(B0 + boff);
        b1 = *reinterpret_cast<const short8*>(B0 + boff + 1024);
        __builtin_amdgcn_s_setprio(1);
        #pragma unroll
        for (int i = 0; i < 8; i++) {
            acc[i][0] = __builtin_amdgcn_mfma_f32_16x16x32_bf16(af[i], b0, acc[i][0], 0, 0, 0);
            acc[i][1] = __builtin_amdgcn_mfma_f32_16x16x32_bf16(af[i], b1, acc[i][1], 0, 0, 0);
        }
        __builtin_amdgcn_s_setprio(0);
        SBAR();

        // ---- p1: slice0, acc cols 2,3. Issue u=b4+7 (B-s1 of t+1).
        if (t < 15) STAGE(b4 + 7);
        b0 = *reinterpret_cast<const short8*>(B0 + boff + 2048);
        b1 = *reinterpret_cast<const short8*>(B0 + boff + 3072);
        __builtin_amdgcn_s_setprio(1);
        #pragma unroll
        for (int i = 0; i < 8; i++) {
            acc[i][2] = __builtin_amdgcn_mfma_f32_16x16x32_bf16(af[i], b0, acc[i][2], 0, 0, 0);
            acc[i][3] = __builtin_amdgcn_mfma_f32_16x16x32_bf16(af[i], b1, acc[i][3], 0, 0, 0);
        }
        __builtin_amdgcn_s_setprio(0);
        // guard units b4+2,b4+3 (read at p2): younger = b4+4..b4+7 = 8 loads
        if (t < 15) { VMCNT(8); } else { VMCNT(0); }
        SBAR();

        // ---- p2: slice1, acc cols 0,1. Issue u=b4+8 (A-s0 of t+2).
        if (t < 14) STAGE(b4 + 8);
        #pragma unroll
        for (int i = 0; i < 8; i++)
            af[i] = *reinterpret_cast<const short8*>(A1 + aoff + i * 1024);
        b0 = *reinterpret_cast<const short8*>(B1 + boff);
        b1 = *reinterpret_cast<const short8*>(B1 + boff + 1024);
        __builtin_amdgcn_s_setprio(1);
        #pragma unroll
        for (int i = 0; i < 8; i++) {
            acc[i][0] = __builtin_amdgcn_mfma_f32_16x16x32_bf16(af[i], b0, acc[i][0], 0, 0, 0);
            acc[i][1] = __builtin_amdgcn_mfma_f32_16x16x32_bf16(af[i], b1, acc[i][1], 0, 0, 0);
        }
        __builtin_amdgcn_s_setprio(0);
        SBAR();

        // ---- p3: slice1, acc cols 2,3. Issue u=b4+9 (B-s0 of t+2).
        if (t < 14) STAGE(b4 + 9);
        b0 = *reinterpret_cast<const short8*>(B1 + boff + 2048);
        b1 = *reinterpret_cast<const short8*>(B1 + boff + 3072);
        __builtin_amdgcn_s_setprio(1);
        #pragma unroll
        for (int i = 0; i < 8; i++) {
            acc[i][2] = __builtin_amdgcn_mfma_f32_16x16x32_bf16(af[i], b0, acc[i][2], 0, 0, 0);
            acc[i][3] = __builtin_amdgcn_mfma_f32_16x16x32_bf16(af[i], b1, acc[i][3], 0, 0, 0);
        }
        __builtin_amdgcn_s_setprio(0);
        // guard units b4+4,b4+5 (read at p0 of t+1): younger = b4+6..b4+9 = 8 loads
        if (t < 14) { VMCNT(8); } else if (t == 14) { VMCNT(4); }
        SBAR();
    }
    #undef STAGE

    // epilogue: + bias, scatter to original rows. C/D map: col=lane&15, row=(lane>>4)*4+reg
    const int ccol = lane & 15;
    const int crow = (lane >> 4) << 2;
    float bv[4];
    const float* bp = bias + branch * OUTF + n0 + wn;
    #pragma unroll
    for (int fn = 0; fn < 4; fn++) bv[fn] = bp[fn * 16 + ccol];
    #pragma unroll
    for (int fm = 0; fm < 8; fm++) {
        #pragma unroll
        for (int j = 0; j < 4; j++) {
            int gm = lt * 256 + wm + fm * 16 + crow + j;
            if (gm < cnt) {
                int orow = rowlist[rbase + gm];
                float* orp = out + (size_t)orow * OUTF + n0 + wn;
                #pragma unroll
                for (int fn = 0; fn < 4; fn++)
                    orp[fn * 16 + ccol] = acc[fm][fn][j] + bv[fn];
            }
        }
    }
}

// ---------------- fallback (direct, fp32 W) if ws is too small ----------------
__global__ __launch_bounds__(256, 3)
void k_gemm_fb(const float* __restrict__ x,
               const float* __restrict__ wf,
               const float* __restrict__ bias,
               const int* __restrict__ ws_i,
               const int* __restrict__ rowlist,
               float* __restrict__ out) {
    __shared__ unsigned short As[128][72];
    __shared__ unsigned short Bs[128][72];

    int t = (int)blockIdx.x;
    int branch = -1, ltile = 0, cnt = 0, rbase = 0;
    #pragma unroll
    for (int b = 0; b < NBR; b++) {
        if (branch < 0) {
            int c = ws_i[b];
            int nt = (c + 255) >> 8;  // segments 256-aligned; tiles of 128 within
            nt <<= 1;
            if (t < nt) { branch = b; ltile = t; cnt = c; rbase = ws_i[4 + b]; }
            else t -= nt;
        }
    }
    if (branch < 0) return;

    const int tid = threadIdx.x;
    const int lane = tid & 63;
    const int wid = tid >> 6;
    const int wm = (wid & 1) << 6;
    const int wn = (wid >> 1) << 6;
    const int n0 = (int)blockIdx.y * 128;

    const int srow = tid >> 1;
    const int scol = (tid & 1) << 5;

    const int gmrow = ltile * 128 + srow;
    const int grow = (gmrow < cnt) ? rowlist[rbase + gmrow] : -1;
    const float* xsrc = x + (size_t)(grow < 0 ? 0 : grow) * OUTF + scol;
    const float* wfsrc = wf + ((size_t)branch << 20) + (size_t)(n0 + srow) * OUTF + scol;

    f32x4 acc[4][4];
    #pragma unroll
    for (int i = 0; i < 4; i++)
        #pragma unroll
        for (int j = 0; j < 4; j++)
            acc[i][j] = (f32x4){0.f, 0.f, 0.f, 0.f};

    for (int k0 = 0; k0 < OUTF; k0 += 64) {
        {
            unsigned short* dst = &As[srow][scol];
            if (grow >= 0) {
                const float4* s4 = reinterpret_cast<const float4*>(xsrc + k0);
                #pragma unroll
                for (int i = 0; i < 8; i += 2)
                    *reinterpret_cast<short8*>(dst + i * 4) = pack8(s4[i], s4[i + 1]);
            } else {
                short8 z = (short8){0, 0, 0, 0, 0, 0, 0, 0};
                #pragma unroll
                for (int i = 0; i < 8; i += 2) *reinterpret_cast<short8*>(dst + i * 4) = z;
            }
        }
        {
            unsigned short* dst = &Bs[srow][scol];
            const float4* s4 = reinterpret_cast<const float4*>(wfsrc + k0);
            #pragma unroll
            for (int i = 0; i < 8; i += 2)
                *reinterpret_cast<short8*>(dst + i * 4) = pack8(s4[i], s4[i + 1]);
        }
        __syncthreads();
        #pragma unroll
        for (int kk = 0; kk < 64; kk += 32) {
            const int krd = kk + (lane >> 4) * 8;
            short8 af[4], bf_[4];
            #pragma unroll
            for (int i = 0; i < 4; i++)
                af[i] = *reinterpret_cast<const short8*>(&As[wm + i * 16 + (lane & 15)][krd]);
            #pragma unroll
            for (int i = 0; i < 4; i++)
                bf_[i] = *reinterpret_cast<const short8*>(&Bs[wn + i * 16 + (lane & 15)][krd]);
            #pragma unroll
            for (int i = 0; i < 4; i++)
                #pragma unroll
                for (int j = 0; j < 4; j++)
                    acc[i][j] = __builtin_amdgcn_mfma_f32_16x16x32_bf16(af[i], bf_[j], acc[i][j], 0, 0, 0);
        }
        __syncthreads();
    }

    const int ccol = lane & 15;
    const int crow = (lane >> 4) << 2;
    float bv[4];
    const float* bp = bias + branch * OUTF + n0 + wn;
    #pragma unroll
    for (int fn = 0; fn < 4; fn++) bv[fn] = bp[fn * 16 + ccol];
    #pragma unroll
    for (int fm = 0; fm < 4; fm++) {
        #pragma unroll
        for (int j = 0; j < 4; j++) {
            int gm = ltile * 128 + wm + fm * 16 + crow + j;
            if (gm < cnt) {
                int orow = rowlist[rbase + gm];
                float* orp = out + (size_t)orow * OUTF + n0 + wn;
                #pragma unroll
                for (int fn = 0; fn < 4; fn++)
                    orp[fn * 16 + ccol] = acc[fm][fn][j] + bv[fn];
            }
        }
    }
}

extern "C" void kernel_launch(void* const* d_in, const int* in_sizes, int n_in,
                              void* d_out, int out_size, void* d_ws, size_t ws_size,
                              hipStream_t stream) {
    const float* x = (const float*)d_in[0];
    const int* feat = (const int*)d_in[1];
    const float* w = (const float*)d_in[2];
    const float* bias = (const float*)d_in[3];
    float* out = (float*)d_out;

    char* ws = (char*)d_ws;
    int* ws_i = (int*)ws;
    int* rowlist = (int*)(ws + 256);                       // 66560*4 = 266 KB
    const size_t WB_OFF = (size_t)512 << 10;               // 512 KB
    const size_t XB_OFF = (size_t)9 << 20;                 // 9 MB
    unsigned short* wb = (unsigned short*)(ws + WB_OFF);   // 8 MB bf16 W
    unsigned short* xb = (unsigned short*)(ws + XB_OFF);   // 136.3 MB bf16 x (permuted)
    const size_t need_full = XB_OFF + (size_t)XBROWS * 2048;

    (void)hipMemsetAsync(ws_i, 0, 64, stream);
    k_count<<<NROWS / 256, 256, 0, stream>>>(feat, ws_i);
    k_prefix<<<1, 64, 0, stream>>>(ws_i);
    k_fill<<<NROWS / 256, 256, 0, stream>>>(feat, ws_i, rowlist);

    if (ws_size >= need_full) {
        k_convw<<<(NBR * OUTF * OUTF) / (256 * 8), 256, 0, stream>>>(w, wb);
        k_convx<<<(XBROWS * 128) / 512, 512, 0, stream>>>(x, rowlist, xb);
        (void)hipFuncSetAttribute((const void*)k_gemm6,
                                  hipFuncAttributeMaxDynamicSharedMemorySize, 147456);
        k_gemm6<<<NWG, 512, 147456, stream>>>(xb, wb, bias, ws_i, rowlist, out);
    } else {
        dim3 grid(NROWS / 128 + 2 * NBR, OUTF / 128);
        k_gemm_fb<<<grid, 256, 0, stream>>>(x, w, bias, ws_i, rowlist, out);
    }
}

// Round 8
// 338.748 us; speedup vs baseline: 1.0760x; 1.0760x over previous
//
#include <hip/hip_runtime.h>
#include <hip/hip_bf16.h>

#define OUTF 1024
#define NROWS 65536
#define NBR 4
#define XBROWS 66560     // rowlist capacity (256-aligned branch segments)
#define NWG 4160         // 520 M-tiles(128) * 8 N-tiles(128), %8==0

typedef __attribute__((ext_vector_type(8))) short short8;
typedef __attribute__((ext_vector_type(4))) float f32x4;

__device__ inline unsigned short f2bf(float f) {
    return __builtin_bit_cast(unsigned short, (__bf16)f);
}
__device__ inline void gload_lds16(const void* g, void* l) {
    __builtin_amdgcn_global_load_lds(
        (const __attribute__((address_space(1))) void*)g,
        (__attribute__((address_space(3))) void*)l, 16, 0, 0);
}
__device__ inline short8 pack8(float4 a, float4 b) {
    short8 o;
    o[0] = (short)f2bf(a.x); o[1] = (short)f2bf(a.y);
    o[2] = (short)f2bf(a.z); o[3] = (short)f2bf(a.w);
    o[4] = (short)f2bf(b.x); o[5] = (short)f2bf(b.y);
    o[6] = (short)f2bf(b.z); o[7] = (short)f2bf(b.w);
    return o;
}
__device__ inline short8 pack8v(f32x4 a, f32x4 b) {
    short8 o;
    o[0] = (short)f2bf(a[0]); o[1] = (short)f2bf(a[1]);
    o[2] = (short)f2bf(a[2]); o[3] = (short)f2bf(a[3]);
    o[4] = (short)f2bf(b[0]); o[5] = (short)f2bf(b[1]);
    o[6] = (short)f2bf(b[2]); o[7] = (short)f2bf(b[3]);
    return o;
}

// ws int layout: [0..3] counts, [4..7] segment bases (256-aligned), [8..11] fill pos
__global__ void k_count(const int* __restrict__ feat, int* __restrict__ cnt) {
    __shared__ int lc[NBR];
    int tid = threadIdx.x;
    if (tid < NBR) lc[tid] = 0;
    __syncthreads();
    int r = blockIdx.x * 256 + tid;
    int b = 26 - __clz(feat[r]);  // 32->0, 64->1, 128->2, 256->3
    atomicAdd(&lc[b], 1);
    __syncthreads();
    if (tid < NBR && lc[tid]) atomicAdd(&cnt[tid], lc[tid]);
}

__global__ void k_prefix(int* __restrict__ ws) {
    if (threadIdx.x == 0) {
        int s = 0;
        for (int b = 0; b < NBR; b++) {
            ws[4 + b] = s;
            s = (s + ws[b] + 255) & ~255;
            ws[8 + b] = 0;
        }
    }
}

__global__ void k_fill(const int* __restrict__ feat, int* __restrict__ ws,
                       int* __restrict__ rowlist) {
    int tid = threadIdx.x;
    int lane = tid & 63;
    int r = blockIdx.x * 256 + tid;
    int b = 26 - __clz(feat[r]);
    #pragma unroll
    for (int bb = 0; bb < NBR; bb++) {
        unsigned long long mask = __ballot(b == bb);
        int leader = __ffsll((long long)mask) - 1;
        int cntw = __popcll(mask);
        int basepos = 0;
        if (lane == leader) basepos = atomicAdd(&ws[8 + bb], cntw);
        basepos = __shfl(basepos, leader < 0 ? 0 : leader);
        if (b == bb) {
            int prefix = __popcll(mask & ((1ull << lane) - 1ull));
            rowlist[ws[4 + bb] + basepos + prefix] = r;
        }
    }
}

// W fp32 -> bf16, pre-swizzled (verified rounds 5/6: zero read conflicts):
// wsw[br][n][kw*128 + cb] = bf16(W[br][n][kw*64 + ((cb ^ ((n&7)<<4)) >> 1)])
__global__ void k_convw(const float* __restrict__ w, unsigned short* __restrict__ wsw) {
    int idx = (int)blockIdx.x * 256 + (int)threadIdx.x;   // 16B chunks
    int branch = idx >> 17;
    int rem = idx & 131071;
    int n = rem >> 7;
    int cb = (rem & 127) << 4;
    int kw = cb >> 7;
    int wb_ = cb & 127;
    int src = kw * 64 + ((wb_ ^ ((n & 7) << 4)) >> 1);
    const float4* s = reinterpret_cast<const float4*>(
        w + ((size_t)branch << 20) + (size_t)n * OUTF + src);
    char* dst = reinterpret_cast<char*>(wsw) + ((size_t)branch << 21) + (size_t)n * 2048 + cb;
    *reinterpret_cast<short8*>(dst) = pack8(s[0], s[1]);
}

// 128x128x64 GEMM, 4 waves (2M x 2N, 64x64 each), single-buffered 48 KiB LDS,
// m97 2-barrier loop, 3 blocks/CU. A gathered DIRECTLY from fp32 x via
// global_load_lds (per-lane source addr, inverse-swizzled within each row's
// 256B K-window); fp32->bf16 conversion happens in the fragment read.
// B from pre-swizzled bf16 wsw. All fragment ds_reads <=2-way bank alias.
__global__ __launch_bounds__(256, 3)
void k_gemm7(const float* __restrict__ x,
             const unsigned short* __restrict__ wsw,
             const float* __restrict__ bias,
             const int* __restrict__ ws_i,
             const int* __restrict__ rowlist,
             float* __restrict__ out) {
    __shared__ char Alds[32768];   // 128 rows x 256 B fp32 (16B-chunk swizzled)
    __shared__ char Blds[16384];   // 128 rows x 128 B bf16 (16B-chunk swizzled)

    // XCD chunking, M-major within chunk (A-panel reused across 8 N-tiles in L2)
    const int d = (int)blockIdx.x;
    const int work = (d & 7) * (NWG >> 3) + (d >> 3);
    const int mtile = work >> 3;
    const int ntile = work & 7;

    int branch = -1, lt = 0, cnt = 0, rbase = 0;
    int t_ = mtile;
    #pragma unroll
    for (int b = 0; b < NBR; b++) {
        if (branch < 0) {
            int c = ws_i[b];
            int nt = (c + 127) >> 7;
            if (t_ < nt) { branch = b; lt = t_; cnt = c; rbase = ws_i[4 + b]; }
            else t_ -= nt;
        }
    }
    if (branch < 0) return;

    const int tid = (int)threadIdx.x;
    const int lane = tid & 63;
    const int wid = tid >> 6;
    const int wm = (wid & 1) << 6;   // 0/64
    const int wn = (wid >> 1) << 6;  // 0/64
    const int n0 = ntile << 7;
    const int row0 = rbase + (lt << 7);

    // ---- A gather sources: instr i covers tile-row tr = i*16 + (tid>>4),
    // 16B chunk c16 = tid&15 of the 256B K-window; source chunk = c16 ^ (tr&7)
    const char* aP[8];
    {
        const int rsub = tid >> 4;                       // 0..15
        const int sc = ((tid & 15) << 4) ^ ((rsub & 7) << 4);
        #pragma unroll
        for (int i = 0; i < 8; i++) {
            int rl = rowlist[row0 + i * 16 + rsub];
            if ((unsigned)rl >= NROWS) rl = 0;           // pad-gap garbage -> row 0
            aP[i] = reinterpret_cast<const char*>(x + (size_t)rl * OUTF) + sc;
        }
    }
    // ---- B sources: instr i covers row i*32 + (tid>>3), chunk tid&7 (swizzle baked in wsw)
    const char* bP[4];
    #pragma unroll
    for (int i = 0; i < 4; i++) {
        int rn = i * 32 + (tid >> 3);
        bP[i] = reinterpret_cast<const char*>(wsw) + ((size_t)branch << 21)
                + (size_t)(n0 + rn) * 2048 + ((tid & 7) << 4);
    }
    const int dst16 = tid << 4;

    f32x4 acc[4][4];
    #pragma unroll
    for (int i = 0; i < 4; i++)
        #pragma unroll
        for (int j = 0; j < 4; j++) acc[i][j] = (f32x4){0.f, 0.f, 0.f, 0.f};

    const int q = lane >> 4;     // k-quarter
    const int lr = lane & 15;

    for (int kt = 0; kt < 16; ++kt) {
        // stage: A window advances 256 B/step, B window 128 B/step
        #pragma unroll
        for (int i = 0; i < 8; i++)
            gload_lds16(aP[i] + kt * 256, Alds + i * 4096 + dst16);
        #pragma unroll
        for (int i = 0; i < 4; i++)
            gload_lds16(bP[i] + kt * 128, Blds + i * 4096 + dst16);
        __syncthreads();   // drains vmcnt+lgkm, then barrier

        #pragma unroll
        for (int ks = 0; ks < 2; ks++) {
            short8 af[4], bfr[4];
            #pragma unroll
            for (int i = 0; i < 4; i++) {
                const int r = wm + i * 16 + lr;
                const int off = ((ks << 7) + (q << 5)) ^ ((r & 7) << 4);
                const f32x4 v0 = *reinterpret_cast<const f32x4*>(Alds + r * 256 + off);
                const f32x4 v1 = *reinterpret_cast<const f32x4*>(Alds + r * 256 + (off ^ 16));
                af[i] = pack8v(v0, v1);   // fp32 -> bf16 here (cvt_pk pairs)
            }
            #pragma unroll
            for (int j = 0; j < 4; j++) {
                const int r = wn + j * 16 + lr;
                const int off = ((ks << 6) + (q << 4)) ^ ((r & 7) << 4);
                bfr[j] = *reinterpret_cast<const short8*>(Blds + r * 128 + off);
            }
            __builtin_amdgcn_s_setprio(1);
            #pragma unroll
            for (int i = 0; i < 4; i++)
                #pragma unroll
                for (int j = 0; j < 4; j++)
                    acc[i][j] = __builtin_amdgcn_mfma_f32_16x16x32_bf16(af[i], bfr[j], acc[i][j], 0, 0, 0);
            __builtin_amdgcn_s_setprio(0);
        }
        __syncthreads();
    }

    // epilogue: + bias, scatter to original rows. C/D map: col=lane&15, row=(lane>>4)*4+reg
    const int ccol = lane & 15;
    const int crow = (lane >> 4) << 2;
    float bv[4];
    const float* bp = bias + branch * OUTF + n0 + wn;
    #pragma unroll
    for (int fn = 0; fn < 4; fn++) bv[fn] = bp[fn * 16 + ccol];
    #pragma unroll
    for (int fm = 0; fm < 4; fm++) {
        #pragma unroll
        for (int j = 0; j < 4; j++) {
            int gm = (lt << 7) + wm + fm * 16 + crow + j;
            if (gm < cnt) {
                int orow = rowlist[rbase + gm];
                float* orp = out + (size_t)orow * OUTF + n0 + wn;
                #pragma unroll
                for (int fn = 0; fn < 4; fn++)
                    orp[fn * 16 + ccol] = acc[fm][fn][j] + bv[fn];
            }
        }
    }
}

// ---------------- fallback (direct, fp32 W) if ws is too small ----------------
__global__ __launch_bounds__(256, 3)
void k_gemm_fb(const float* __restrict__ x,
               const float* __restrict__ wf,
               const float* __restrict__ bias,
               const int* __restrict__ ws_i,
               const int* __restrict__ rowlist,
               float* __restrict__ out) {
    __shared__ unsigned short As[128][72];
    __shared__ unsigned short Bs[128][72];

    int t = (int)blockIdx.x;
    int branch = -1, ltile = 0, cnt = 0, rbase = 0;
    #pragma unroll
    for (int b = 0; b < NBR; b++) {
        if (branch < 0) {
            int c = ws_i[b];
            int nt = (c + 127) >> 7;
            if (t < nt) { branch = b; ltile = t; cnt = c; rbase = ws_i[4 + b]; }
            else t -= nt;
        }
    }
    if (branch < 0) return;

    const int tid = threadIdx.x;
    const int lane = tid & 63;
    const int wid = tid >> 6;
    const int wm = (wid & 1) << 6;
    const int wn = (wid >> 1) << 6;
    const int n0 = (int)blockIdx.y * 128;

    const int srow = tid >> 1;
    const int scol = (tid & 1) << 5;

    const int gmrow = ltile * 128 + srow;
    const int grow = (gmrow < cnt) ? rowlist[rbase + gmrow] : -1;
    const float* xsrc = x + (size_t)(grow < 0 ? 0 : grow) * OUTF + scol;
    const float* wfsrc = wf + ((size_t)branch << 20) + (size_t)(n0 + srow) * OUTF + scol;

    f32x4 acc[4][4];
    #pragma unroll
    for (int i = 0; i < 4; i++)
        #pragma unroll
        for (int j = 0; j < 4; j++)
            acc[i][j] = (f32x4){0.f, 0.f, 0.f, 0.f};

    for (int k0 = 0; k0 < OUTF; k0 += 64) {
        {
            unsigned short* dst = &As[srow][scol];
            if (grow >= 0) {
                const float4* s4 = reinterpret_cast<const float4*>(xsrc + k0);
                #pragma unroll
                for (int i = 0; i < 8; i += 2)
                    *reinterpret_cast<short8*>(dst + i * 4) = pack8(s4[i], s4[i + 1]);
            } else {
                short8 z = (short8){0, 0, 0, 0, 0, 0, 0, 0};
                #pragma unroll
                for (int i = 0; i < 8; i += 2) *reinterpret_cast<short8*>(dst + i * 4) = z;
            }
        }
        {
            unsigned short* dst = &Bs[srow][scol];
            const float4* s4 = reinterpret_cast<const float4*>(wfsrc + k0);
            #pragma unroll
            for (int i = 0; i < 8; i += 2)
                *reinterpret_cast<short8*>(dst + i * 4) = pack8(s4[i], s4[i + 1]);
        }
        __syncthreads();
        #pragma unroll
        for (int kk = 0; kk < 64; kk += 32) {
            const int krd = kk + (lane >> 4) * 8;
            short8 af[4], bf_[4];
            #pragma unroll
            for (int i = 0; i < 4; i++)
                af[i] = *reinterpret_cast<const short8*>(&As[wm + i * 16 + (lane & 15)][krd]);
            #pragma unroll
            for (int i = 0; i < 4; i++)
                bf_[i] = *reinterpret_cast<const short8*>(&Bs[wn + i * 16 + (lane & 15)][krd]);
            #pragma unroll
            for (int i = 0; i < 4; i++)
                #pragma unroll
                for (int j = 0; j < 4; j++)
                    acc[i][j] = __builtin_amdgcn_mfma_f32_16x16x32_bf16(af[i], bf_[j], acc[i][j], 0, 0, 0);
        }
        __syncthreads();
    }

    const int ccol = lane & 15;
    const int crow = (lane >> 4) << 2;
    float bv[4];
    const float* bp = bias + branch * OUTF + n0 + wn;
    #pragma unroll
    for (int fn = 0; fn < 4; fn++) bv[fn] = bp[fn * 16 + ccol];
    #pragma unroll
    for (int fm = 0; fm < 4; fm++) {
        #pragma unroll
        for (int j = 0; j < 4; j++) {
            int gm = ltile * 128 + wm + fm * 16 + crow + j;
            if (gm < cnt) {
                int orow = rowlist[rbase + gm];
                float* orp = out + (size_t)orow * OUTF + n0 + wn;
                #pragma unroll
                for (int fn = 0; fn < 4; fn++)
                    orp[fn * 16 + ccol] = acc[fm][fn][j] + bv[fn];
            }
        }
    }
}

extern "C" void kernel_launch(void* const* d_in, const int* in_sizes, int n_in,
                              void* d_out, int out_size, void* d_ws, size_t ws_size,
                              hipStream_t stream) {
    const float* x = (const float*)d_in[0];
    const int* feat = (const int*)d_in[1];
    const float* w = (const float*)d_in[2];
    const float* bias = (const float*)d_in[3];
    float* out = (float*)d_out;

    char* ws = (char*)d_ws;
    int* ws_i = (int*)ws;
    int* rowlist = (int*)(ws + 256);                       // 66560*4 = 266 KB
    const size_t WSW_OFF = (size_t)512 << 10;              // 512 KB
    unsigned short* wsw = (unsigned short*)(ws + WSW_OFF); // 8 MB bf16 W (pre-swizzled)
    const size_t need = WSW_OFF + (size_t)NBR * OUTF * OUTF * 2;  // ~8.9 MB

    (void)hipMemsetAsync(ws_i, 0, 64, stream);
    k_count<<<NROWS / 256, 256, 0, stream>>>(feat, ws_i);
    k_prefix<<<1, 64, 0, stream>>>(ws_i);
    k_fill<<<NROWS / 256, 256, 0, stream>>>(feat, ws_i, rowlist);

    if (ws_size >= need) {
        k_convw<<<2048, 256, 0, stream>>>(w, wsw);
        k_gemm7<<<NWG, 256, 0, stream>>>(x, wsw, bias, ws_i, rowlist, out);
    } else {
        dim3 grid(NROWS / 128 + NBR, OUTF / 128);
        k_gemm_fb<<<grid, 256, 0, stream>>>(x, w, bias, ws_i, rowlist, out);
    }
}